// Round 12
// baseline (45.062 us; speedup 1.0000x reference)
//
#include <hip/hip_runtime.h>
#include <math.h>

namespace {
constexpr int NB   = 8;    // batch
constexpr int NWIN = 128;  // WIN
constexpr int NK   = 256;  // K (feature/attention dim)
constexpr int NE   = 256;  // E = 2*WIN

typedef float v2f __attribute__((ext_vector_type(2)));

// ---------------------------------------------------------------------------
// Kernel 1: projections. 512 blocks x 512 threads -> 4 waves/SIMD.
// thread = (i = t&255, eh = t>>8): each owns 2 of the block's 4 e's.
// No LDS, no barrier. W reads wave-uniform (s_load); x reads lane-coalesced
// (the 2x x re-read between e-halves hits per-CU L1).
//   hi [b][i][e] = sum_w x[b][w][i] * W_lin[e][w]
//   hjT[b][e][j] = sum_w x[b][w][j] * W_lin[e][WIN+w] + b_lin[e]
// ---------------------------------------------------------------------------
__global__ __launch_bounds__(512) void k1_proj(
    const float* __restrict__ x, const float* __restrict__ W,
    const float* __restrict__ bl, float* __restrict__ hi,
    float* __restrict__ hjT)
{
  const int b  = blockIdx.x >> 6;                       // 0..7
  const int e0 = ((blockIdx.x & 63) << 2) + ((threadIdx.x >> 8) << 1);
  const int i  = threadIdx.x & 255;

  float a1x = 0.f, a1y = 0.f, a2x = 0.f, a2y = 0.f;
  const float* xb = x + (size_t)b * NWIN * NK + i;
  const float* Wr = W + (size_t)e0 * (2 * NWIN);
#pragma unroll 8
  for (int w = 0; w < NWIN; ++w) {
    const float xv = xb[(size_t)w * NK];
    a1x = fmaf(xv, Wr[w], a1x);              // W1 row e0
    a2x = fmaf(xv, Wr[NWIN + w], a2x);       // W2 row e0
    a1y = fmaf(xv, Wr[2 * NWIN + w], a1y);   // W1 row e0+1
    a2y = fmaf(xv, Wr[3 * NWIN + w], a2y);   // W2 row e0+1
  }
  *reinterpret_cast<float2*>(hi + ((size_t)(b * NK + i)) * NE + e0) =
      make_float2(a1x, a1y);
  hjT[((size_t)(b * NE + e0)) * NK + i]     = a2x + bl[e0];
  hjT[((size_t)(b * NE + e0 + 1)) * NK + i] = a2y + bl[e0 + 1];
}

// ---------------------------------------------------------------------------
// Kernel 2: unchanged from round 10 (i-tile 8, 1024 threads, grid 256).
// ---------------------------------------------------------------------------
__global__ __launch_bounds__(1024, 4) void k2_attn(
    const float* __restrict__ x, const float* __restrict__ a_vec,
    const float* __restrict__ bias, const float* __restrict__ hi,
    const float* __restrict__ hjT, float* __restrict__ out)
{
  // smA: [0..2047] hi tile (8 rows x 256), reused as attn after softmax;
  //      [2048..2303] a8 = 0.8*a.
  __shared__ __align__(16) float smA[2304];
  // smB: sred[8 eq][8 ii][256 j] = 64 KB.
  __shared__ __align__(16) float smB[16384];

  const int b    = blockIdx.x >> 5;
  const int i0   = (blockIdx.x & 31) << 3;
  const int t    = threadIdx.x;
  const int lane = t & 63, wave = t >> 6;

  // ---- stage hi tile (2048 floats) + 0.8*a ----
  if (t < 512) {
    ((float4*)smA)[t] =
        ((const float4*)(hi + ((size_t)(b * NK + i0)) * NE))[t];
  } else if (t < 576) {
    const float4 av = ((const float4*)a_vec)[t - 512];
    ((float4*)(smA + 2048))[t - 512] =
        make_float4(0.8f * av.x, 0.8f * av.y, 0.8f * av.z, 0.8f * av.w);
  }
  __syncthreads();

  // ---- main relu loop: wave = (eq, jh), lane -> j-pair ----
  {
    const int eq = wave & 7, jh = wave >> 3;
    const int j0 = jh * 128 + lane * 2;
    v2f s2[8];
#pragma unroll
    for (int ii = 0; ii < 8; ++ii) s2[ii] = (v2f)0.f;
    v2f aj2 = (v2f)0.f;

    const float* hjb = hjT + (size_t)b * NE * NK + j0;

#pragma unroll 2
    for (int ec = 0; ec < 8; ++ec) {
      const int e = eq * 32 + ec * 4;
      v2f h2[4];
#pragma unroll
      for (int k = 0; k < 4; ++k)
        h2[k] = *reinterpret_cast<const v2f*>(hjb + (size_t)(e + k) * NK);
      float a4[4];
      *reinterpret_cast<float4*>(a4) =
          *reinterpret_cast<const float4*>(smA + 2048 + e);
#pragma unroll
      for (int k = 0; k < 4; ++k)
        aj2 = __builtin_elementwise_fma((v2f)a4[k], h2[k], aj2);
#pragma unroll
      for (int ii = 0; ii < 8; ++ii) {
        float g[4];
        *reinterpret_cast<float4*>(g) =
            *reinterpret_cast<const float4*>(smA + ii * NE + e);
#pragma unroll
        for (int k = 0; k < 4; ++k) {
          v2f z = h2[k] + (v2f)g[k];                   // v_pk_add_f32
          z = __builtin_elementwise_max(z, (v2f)0.f);
          s2[ii] = __builtin_elementwise_fma((v2f)a4[k], z, s2[ii]);
        }
      }
    }

    // fold 0.25*aj into every ii slot; Sum_eq gives relu-sum + 0.25*aj.
    const v2f qv = (v2f)0.25f;
#pragma unroll
    for (int ii = 0; ii < 8; ++ii) {
      const v2f o = __builtin_elementwise_fma(qv, aj2, s2[ii]);
      *reinterpret_cast<v2f*>(&smB[(eq * 8 + ii) * NK + j0]) = o;
    }
  }
  __syncthreads();

  // ---- softmax over j: waves 0-7, wave = row ii (overwrites hi w/ attn) ----
  if (wave < 8) {
    const int ii = wave;
    float ev[4];
    float mmax = -INFINITY;
#pragma unroll
    for (int r = 0; r < 4; ++r) {
      const int jj = lane + 64 * r;
      float v = bias[(size_t)(i0 + ii) * NK + jj];
#pragma unroll
      for (int qq = 0; qq < 8; ++qq) v += smB[(qq * 8 + ii) * NK + jj];
      ev[r] = v;
      mmax = fmaxf(mmax, v);
    }
#pragma unroll
    for (int o = 32; o; o >>= 1) mmax = fmaxf(mmax, __shfl_xor(mmax, o));
    float ssum = 0.f;
#pragma unroll
    for (int r = 0; r < 4; ++r) { ev[r] = __expf(ev[r] - mmax); ssum += ev[r]; }
#pragma unroll
    for (int o = 32; o; o >>= 1) ssum += __shfl_xor(ssum, o);
    const float inv = 1.f / ssum;
#pragma unroll
    for (int r = 0; r < 4; ++r) smA[ii * NE + lane + 64 * r] = ev[r] * inv;
  }
  __syncthreads();

  // ---- PV: thread = (wv = t>>3, jq = t&7); 8-lane groups share one x row ----
  {
    const int wv = t >> 3, jq = t & 7;
    float acc[8];
#pragma unroll
    for (int ii = 0; ii < 8; ++ii) acc[ii] = 0.f;
    const float* xr = x + (size_t)b * NWIN * NK + (size_t)wv * NK;
#pragma unroll 2
    for (int jc = 0; jc < 8; ++jc) {
      const int j = jc * 32 + jq * 4;
      const float4 xv = *reinterpret_cast<const float4*>(&xr[j]);
#pragma unroll
      for (int ii = 0; ii < 8; ++ii) {
        const float4 at = *reinterpret_cast<const float4*>(&smA[ii * NE + j]);
        acc[ii] = fmaf(at.x, xv.x, acc[ii]);
        acc[ii] = fmaf(at.y, xv.y, acc[ii]);
        acc[ii] = fmaf(at.z, xv.z, acc[ii]);
        acc[ii] = fmaf(at.w, xv.w, acc[ii]);
      }
    }
#pragma unroll
    for (int o = 1; o <= 4; o <<= 1)
#pragma unroll
      for (int ii = 0; ii < 8; ++ii) acc[ii] += __shfl_xor(acc[ii], o);
    if (jq == 0) {
      float4 o4a, o4b;
      o4a.x = 1.f / (1.f + __expf(-acc[0]));
      o4a.y = 1.f / (1.f + __expf(-acc[1]));
      o4a.z = 1.f / (1.f + __expf(-acc[2]));
      o4a.w = 1.f / (1.f + __expf(-acc[3]));
      o4b.x = 1.f / (1.f + __expf(-acc[4]));
      o4b.y = 1.f / (1.f + __expf(-acc[5]));
      o4b.z = 1.f / (1.f + __expf(-acc[6]));
      o4b.w = 1.f / (1.f + __expf(-acc[7]));
      float* op = out + ((size_t)(b * NWIN + wv)) * NK + i0;
      *reinterpret_cast<float4*>(op)     = o4a;
      *reinterpret_cast<float4*>(op + 4) = o4b;
    }
  }
}

}  // namespace

extern "C" void kernel_launch(void* const* d_in, const int* in_sizes, int n_in,
                              void* d_out, int out_size, void* d_ws,
                              size_t ws_size, hipStream_t stream)
{
  const float* x    = (const float*)d_in[0];  // (8,128,256)
  const float* Wlin = (const float*)d_in[1];  // (256,256)
  const float* blin = (const float*)d_in[2];  // (256,)
  const float* avec = (const float*)d_in[3];  // (256,1)
  const float* bias = (const float*)d_in[4];  // (256,256)
  float* out = (float*)d_out;                 // (8,128,256)

  float* hi  = (float*)d_ws;                   // B*K*E floats = 2 MB
  float* hjT = hi + (size_t)NB * NK * NE;      // B*E*K floats = 2 MB

  k1_proj<<<NB * (NE / 4), 512, 0, stream>>>(x, Wlin, blin, hi, hjT);
  k2_attn<<<NB * (NK / 8), 1024, 0, stream>>>(x, avec, bias, hi, hjT, out);
}

// Round 13
// 32.177 us; speedup vs baseline: 1.4004x; 1.4004x over previous
//
#include <hip/hip_runtime.h>
#include <math.h>

namespace {
constexpr int NB   = 8;    // batch
constexpr int NWIN = 128;  // WIN
constexpr int NK   = 256;  // K (feature/attention dim)
constexpr int NE   = 256;  // E = 2*WIN

typedef float v2f __attribute__((ext_vector_type(2)));

// ---------------------------------------------------------------------------
// Kernel 1: projections. 512 blocks x 512 threads -> 4 waves/SIMD.
// thread = (i = t&255, eh): each owns 2 of the block's 4 e's.
// KEY: eh via readfirstlane -> e0 is provably wave-uniform -> W reads stay
// s_loads (scalar cache). R12 regression was this demotion to vector loads.
//   hi [b][i][e] = sum_w x[b][w][i] * W_lin[e][w]
//   hjT[b][e][j] = sum_w x[b][w][j] * W_lin[e][WIN+w] + b_lin[e]
// ---------------------------------------------------------------------------
__global__ __launch_bounds__(512, 4) void k1_proj(
    const float* __restrict__ x, const float* __restrict__ W,
    const float* __restrict__ bl, float* __restrict__ hi,
    float* __restrict__ hjT)
{
  const int b  = blockIdx.x >> 6;                       // 0..7
  const int eh = __builtin_amdgcn_readfirstlane(threadIdx.x >> 8);  // 0/1
  const int e0 = ((blockIdx.x & 63) << 2) + (eh << 1);
  const int i  = threadIdx.x & 255;

  float a1x = 0.f, a1y = 0.f, a2x = 0.f, a2y = 0.f;
  const float* xb = x + (size_t)b * NWIN * NK + i;
  const float* Wr = W + (size_t)e0 * (2 * NWIN);
#pragma unroll 8
  for (int w = 0; w < NWIN; ++w) {
    const float xv = xb[(size_t)w * NK];
    a1x = fmaf(xv, Wr[w], a1x);              // W1 row e0
    a2x = fmaf(xv, Wr[NWIN + w], a2x);       // W2 row e0
    a1y = fmaf(xv, Wr[2 * NWIN + w], a1y);   // W1 row e0+1
    a2y = fmaf(xv, Wr[3 * NWIN + w], a2y);   // W2 row e0+1
  }
  *reinterpret_cast<float2*>(hi + ((size_t)(b * NK + i)) * NE + e0) =
      make_float2(a1x, a1y);
  hjT[((size_t)(b * NE + e0)) * NK + i]     = a2x + bl[e0];
  hjT[((size_t)(b * NE + e0 + 1)) * NK + i] = a2y + bl[e0 + 1];
}

// ---------------------------------------------------------------------------
// Kernel 2: unchanged from round 10 (i-tile 8, 1024 threads, grid 256).
// ---------------------------------------------------------------------------
__global__ __launch_bounds__(1024, 4) void k2_attn(
    const float* __restrict__ x, const float* __restrict__ a_vec,
    const float* __restrict__ bias, const float* __restrict__ hi,
    const float* __restrict__ hjT, float* __restrict__ out)
{
  // smA: [0..2047] hi tile (8 rows x 256), reused as attn after softmax;
  //      [2048..2303] a8 = 0.8*a.
  __shared__ __align__(16) float smA[2304];
  // smB: sred[8 eq][8 ii][256 j] = 64 KB.
  __shared__ __align__(16) float smB[16384];

  const int b    = blockIdx.x >> 5;
  const int i0   = (blockIdx.x & 31) << 3;
  const int t    = threadIdx.x;
  const int lane = t & 63, wave = t >> 6;

  // ---- stage hi tile (2048 floats) + 0.8*a ----
  if (t < 512) {
    ((float4*)smA)[t] =
        ((const float4*)(hi + ((size_t)(b * NK + i0)) * NE))[t];
  } else if (t < 576) {
    const float4 av = ((const float4*)a_vec)[t - 512];
    ((float4*)(smA + 2048))[t - 512] =
        make_float4(0.8f * av.x, 0.8f * av.y, 0.8f * av.z, 0.8f * av.w);
  }
  __syncthreads();

  // ---- main relu loop: wave = (eq, jh), lane -> j-pair ----
  {
    const int eq = wave & 7, jh = wave >> 3;
    const int j0 = jh * 128 + lane * 2;
    v2f s2[8];
#pragma unroll
    for (int ii = 0; ii < 8; ++ii) s2[ii] = (v2f)0.f;
    v2f aj2 = (v2f)0.f;

    const float* hjb = hjT + (size_t)b * NE * NK + j0;

#pragma unroll 2
    for (int ec = 0; ec < 8; ++ec) {
      const int e = eq * 32 + ec * 4;
      v2f h2[4];
#pragma unroll
      for (int k = 0; k < 4; ++k)
        h2[k] = *reinterpret_cast<const v2f*>(hjb + (size_t)(e + k) * NK);
      float a4[4];
      *reinterpret_cast<float4*>(a4) =
          *reinterpret_cast<const float4*>(smA + 2048 + e);
#pragma unroll
      for (int k = 0; k < 4; ++k)
        aj2 = __builtin_elementwise_fma((v2f)a4[k], h2[k], aj2);
#pragma unroll
      for (int ii = 0; ii < 8; ++ii) {
        float g[4];
        *reinterpret_cast<float4*>(g) =
            *reinterpret_cast<const float4*>(smA + ii * NE + e);
#pragma unroll
        for (int k = 0; k < 4; ++k) {
          v2f z = h2[k] + (v2f)g[k];                   // v_pk_add_f32
          z = __builtin_elementwise_max(z, (v2f)0.f);
          s2[ii] = __builtin_elementwise_fma((v2f)a4[k], z, s2[ii]);
        }
      }
    }

    // fold 0.25*aj into every ii slot; Sum_eq gives relu-sum + 0.25*aj.
    const v2f qv = (v2f)0.25f;
#pragma unroll
    for (int ii = 0; ii < 8; ++ii) {
      const v2f o = __builtin_elementwise_fma(qv, aj2, s2[ii]);
      *reinterpret_cast<v2f*>(&smB[(eq * 8 + ii) * NK + j0]) = o;
    }
  }
  __syncthreads();

  // ---- softmax over j: waves 0-7, wave = row ii (overwrites hi w/ attn) ----
  if (wave < 8) {
    const int ii = wave;
    float ev[4];
    float mmax = -INFINITY;
#pragma unroll
    for (int r = 0; r < 4; ++r) {
      const int jj = lane + 64 * r;
      float v = bias[(size_t)(i0 + ii) * NK + jj];
#pragma unroll
      for (int qq = 0; qq < 8; ++qq) v += smB[(qq * 8 + ii) * NK + jj];
      ev[r] = v;
      mmax = fmaxf(mmax, v);
    }
#pragma unroll
    for (int o = 32; o; o >>= 1) mmax = fmaxf(mmax, __shfl_xor(mmax, o));
    float ssum = 0.f;
#pragma unroll
    for (int r = 0; r < 4; ++r) { ev[r] = __expf(ev[r] - mmax); ssum += ev[r]; }
#pragma unroll
    for (int o = 32; o; o >>= 1) ssum += __shfl_xor(ssum, o);
    const float inv = 1.f / ssum;
#pragma unroll
    for (int r = 0; r < 4; ++r) smA[ii * NE + lane + 64 * r] = ev[r] * inv;
  }
  __syncthreads();

  // ---- PV: thread = (wv = t>>3, jq = t&7); 8-lane groups share one x row ----
  {
    const int wv = t >> 3, jq = t & 7;
    float acc[8];
#pragma unroll
    for (int ii = 0; ii < 8; ++ii) acc[ii] = 0.f;
    const float* xr = x + (size_t)b * NWIN * NK + (size_t)wv * NK;
#pragma unroll 2
    for (int jc = 0; jc < 8; ++jc) {
      const int j = jc * 32 + jq * 4;
      const float4 xv = *reinterpret_cast<const float4*>(&xr[j]);
#pragma unroll
      for (int ii = 0; ii < 8; ++ii) {
        const float4 at = *reinterpret_cast<const float4*>(&smA[ii * NE + j]);
        acc[ii] = fmaf(at.x, xv.x, acc[ii]);
        acc[ii] = fmaf(at.y, xv.y, acc[ii]);
        acc[ii] = fmaf(at.z, xv.z, acc[ii]);
        acc[ii] = fmaf(at.w, xv.w, acc[ii]);
      }
    }
#pragma unroll
    for (int o = 1; o <= 4; o <<= 1)
#pragma unroll
      for (int ii = 0; ii < 8; ++ii) acc[ii] += __shfl_xor(acc[ii], o);
    if (jq == 0) {
      float4 o4a, o4b;
      o4a.x = 1.f / (1.f + __expf(-acc[0]));
      o4a.y = 1.f / (1.f + __expf(-acc[1]));
      o4a.z = 1.f / (1.f + __expf(-acc[2]));
      o4a.w = 1.f / (1.f + __expf(-acc[3]));
      o4b.x = 1.f / (1.f + __expf(-acc[4]));
      o4b.y = 1.f / (1.f + __expf(-acc[5]));
      o4b.z = 1.f / (1.f + __expf(-acc[6]));
      o4b.w = 1.f / (1.f + __expf(-acc[7]));
      float* op = out + ((size_t)(b * NWIN + wv)) * NK + i0;
      *reinterpret_cast<float4*>(op)     = o4a;
      *reinterpret_cast<float4*>(op + 4) = o4b;
    }
  }
}

}  // namespace

extern "C" void kernel_launch(void* const* d_in, const int* in_sizes, int n_in,
                              void* d_out, int out_size, void* d_ws,
                              size_t ws_size, hipStream_t stream)
{
  const float* x    = (const float*)d_in[0];  // (8,128,256)
  const float* Wlin = (const float*)d_in[1];  // (256,256)
  const float* blin = (const float*)d_in[2];  // (256,)
  const float* avec = (const float*)d_in[3];  // (256,1)
  const float* bias = (const float*)d_in[4];  // (256,256)
  float* out = (float*)d_out;                 // (8,128,256)

  float* hi  = (float*)d_ws;                   // B*K*E floats = 2 MB
  float* hjT = hi + (size_t)NB * NK * NE;      // B*E*K floats = 2 MB

  k1_proj<<<NB * (NE / 4), 512, 0, stream>>>(x, Wlin, blin, hi, hjT);
  k2_attn<<<NB * (NK / 8), 1024, 0, stream>>>(x, avec, bias, hi, hjT, out);
}